// Round 13
// baseline (9622.833 us; speedup 1.0000x reference)
//
#include <hip/hip_runtime.h>

#define B_ 128
#define S_ 4096
#define IN_ 6
#define N_ 64
#define MOT_ 3
#define UNF 6
#define EPS_ 1e-8f
#define LOG2E 1.4426950408889634f

typedef float v2f __attribute__((ext_vector_type(2)));

// ---- VALU-pipe cross-lane pair-sums over lane bits 4 and 5 ----
__device__ __forceinline__ float red16(float x) {
#if __has_builtin(__builtin_amdgcn_permlane16_swap)
    auto r = __builtin_amdgcn_permlane16_swap(__float_as_int(x), __float_as_int(x),
                                              false, false);
    return __int_as_float((int)r[0]) + __int_as_float((int)r[1]);
#else
    return x + __shfl_xor(x, 16, 64);
#endif
}
__device__ __forceinline__ float red32(float x) {
#if __has_builtin(__builtin_amdgcn_permlane32_swap)
    auto r = __builtin_amdgcn_permlane32_swap(__float_as_int(x), __float_as_int(x),
                                              false, false);
    return __int_as_float((int)r[0]) + __int_as_float((int)r[1]);
#else
    return x + __shfl_xor(x, 32, 64);
#endif
}

// barrier with LDS-only drain (no vmcnt: global loads/stores stay in flight)
__device__ __forceinline__ void lds_barrier() {
    asm volatile("s_waitcnt lgkmcnt(0)" ::: "memory");
    __builtin_amdgcn_s_barrier();
}

// One workgroup per batch chain. 256 threads = 4 waves = 1 wave/SIMD.
// Wave w owns columns w*16..w*16+15; lane l = (cc=l>>4 j-chunk of 16, ii=l&15
// col). Per unfold: 16 synapses/lane as 8 PAIR-RATIONAL combines
//   w0/t0 + w1/t1 = (w0*t1 + w1*t0) * rcp(t0*t1)   (t = 1+exp2(v*A+Bc))
// -> 24 trans instrs (16 exp2 + 8 rcp) instead of 32; the extra ~4 VALU/pair
// issue into the trans-pipe shadow (1 wave/SIMD, separate pipes). Accumulator
// seeded with 0.25*(nbs + cmt*v) (computed in the prior barrier shadow), so
// the post-butterfly tail is just pn*rcp(pd). 2-stage permlane butterfly,
// ONE lgkm-only barrier per unfold, per-lane register sensory (r9 skeleton).
__launch_bounds__(256, 1)
__global__ void ltc_kernel(
    const float* __restrict__ x,
    const float* __restrict__ mean_us, const float* __restrict__ std_us,
    const float* __restrict__ input_w, const float* __restrict__ input_b,
    const float* __restrict__ output_w, const float* __restrict__ output_b,
    const float* __restrict__ gleak, const float* __restrict__ vleak,
    const float* __restrict__ cm,
    const float* __restrict__ sW, const float* __restrict__ sMu,
    const float* __restrict__ sSig, const float* __restrict__ sErev,
    const float* __restrict__ W, const float* __restrict__ Mu,
    const float* __restrict__ Sig, const float* __restrict__ Erev,
    float* __restrict__ out)
{
    const int b    = blockIdx.x;
    const int t    = threadIdx.x;
    const int lane = t & 63;
    const int w    = t >> 6;      // wave 0..3
    const int cc   = lane >> 4;   // j-chunk 0..3 (16 j's each)
    const int ii   = lane & 15;   // column within wave's block
    const int myCol = (w << 4) + ii;
    const int jb   = cc << 4;

    __shared__ __align__(16) float vbuf[2][N_];

    // --- recurrent synapse params: 16 synapses (j=jb..jb+15) of column myCol,
    // packed in pairs for v_pk_fma: t = 1+exp2(v*A + Bc)
    v2f A2[8], B2[8];
    float Wr[16], We[16];
#pragma unroll
    for (int jj = 0; jj < 16; ++jj) {
        int idx = (jb + jj) * N_ + myCol;
        float sg = Sig[idx], m = Mu[idx], ww = W[idx], e = Erev[idx];
        A2[jj >> 1][jj & 1] = -sg * LOG2E;
        B2[jj >> 1][jj & 1] = m * sg * LOG2E;
        Wr[jj] = ww;
        We[jj] = ww * e;
    }

    // --- per-column state consts ---
    const float cmt  = cm[myCol] * (float)UNF;
    const float cmt4 = 0.25f * cmt;
    const float glk  = gleak[myCol];
    const float gv   = glk * vleak[myCol];
    const float dbase = cmt + glk + EPS_;

    // --- sensory params: per-lane, ALL 6 inputs for column myCol ---
    float SA[IN_], SB[IN_], SWe[IN_], SWv[IN_], NS[IN_], NB[IN_];
#pragma unroll
    for (int ci = 0; ci < IN_; ++ci) {
        int idx = ci * N_ + myCol;
        float sg = sSig[idx], m = sMu[idx], ww = sW[idx], e = sErev[idx];
        SA[ci]  = -sg * LOG2E;
        SB[ci]  = m * sg * LOG2E;
        SWv[ci] = ww;
        SWe[ci] = ww * e;
        NS[ci]  = input_w[ci] / std_us[ci];
        NB[ci]  = input_b[ci] - mean_us[ci] / std_us[ci] * input_w[ci];
    }

    // --- output consts (lanes 0..2 of wave 0 hold motor columns 0..2) ---
    float OW = 0.f, OB = 0.f;
    if (t < MOT_) {
        OW = output_w[t] * std_us[t];
        OB = output_b[t] * std_us[t] + mean_us[t];
    }

    const float* xb = x + (size_t)b * S_ * IN_;
    float* ob = out + (size_t)b * S_ * MOT_;

    if (t < N_) vbuf[0][t] = 0.f;

    // step-0 inputs (blocking, one-time); force VMEM via VGPR offset
    float xc[IN_];
    {
        int off = 0;
        asm volatile("" : "+v"(off));
        float2 x01 = *(const float2*)(xb + off);
        float2 x23 = *(const float2*)(xb + off + 2);
        float2 x45 = *(const float2*)(xb + off + 4);
        xc[0] = x01.x; xc[1] = x01.y; xc[2] = x23.x;
        xc[3] = x23.y; xc[4] = x45.x; xc[5] = x45.y;
    }
    __syncthreads();

    float v_my = 0.f;

    for (int s = 0; s < S_; ++s) {
        // prefetch next step's inputs (VMEM, stays in flight across lgkm waits)
        const int s1 = (s + 1 < S_) ? (s + 1) : s;
        int off = s1 * IN_;
        asm volatile("" : "+v"(off));
        float2 p01 = *(const float2*)(xb + off);
        float2 p23 = *(const float2*)(xb + off + 2);
        float2 p45 = *(const float2*)(xb + off + 4);

        // per-lane sensory fold for this step (registers only; overlaps k=0's
        // v-read + sigmoid phase, consumed only after k=0's butterfly)
        float wns = 0.f, wds = 0.f;
#pragma unroll
        for (int ci = 0; ci < IN_; ++ci) {
            float u  = fmaf(xc[ci], NS[ci], NB[ci]);
            float e  = __builtin_amdgcn_exp2f(fmaf(u, SA[ci], SB[ci]));
            float sg = __builtin_amdgcn_rcpf(1.0f + e);
            wns = fmaf(SWe[ci], sg, wns);
            wds = fmaf(SWv[ci], sg, wds);
        }
        // accumulator seeds: butterfly sums 4 partials -> 4 * 0.25 * base = base
        const float nseed = 0.25f * (gv + wns);
        const float dseed = 0.25f * (dbase + wds);
        float sn = fmaf(cmt4, v_my, nseed);   // includes cmt*v for unfold 0

#pragma unroll
        for (int k = 0; k < UNF; ++k) {
            const int p = k & 1;
            // broadcast-read the 16 v's of this lane's j-chunk (4x ds_read_b128)
            float4 q0 = *(const float4*)&vbuf[p][jb];
            float4 q1 = *(const float4*)&vbuf[p][jb + 4];
            float4 q2 = *(const float4*)&vbuf[p][jb + 8];
            float4 q3 = *(const float4*)&vbuf[p][jb + 12];
            const v2f vp[8] = {
                {q0.x, q0.y}, {q0.z, q0.w}, {q1.x, q1.y}, {q1.z, q1.w},
                {q2.x, q2.y}, {q2.z, q2.w}, {q3.x, q3.y}, {q3.z, q3.w}};

            float pn0 = sn,  pd0 = dseed, pn1 = 0.f, pd1 = 0.f;
#pragma unroll
            for (int pi = 0; pi < 8; ++pi) {
                // pair-rational: w0/t0 + w1/t1 = (w0*t1 + w1*t0)*rcp(t0*t1)
                v2f z  = __builtin_elementwise_fma(vp[pi], A2[pi], B2[pi]); // pk_fma
                v2f e  = {__builtin_amdgcn_exp2f(z.x), __builtin_amdgcn_exp2f(z.y)};
                v2f tt = e + 1.0f;                                          // pk_add
                float r  = __builtin_amdgcn_rcpf(tt.x * tt.y);
                float ne = fmaf(We[2*pi], tt.y, We[2*pi+1] * tt.x);
                float nr = fmaf(Wr[2*pi], tt.y, Wr[2*pi+1] * tt.x);
                if (pi & 1) { pn1 = fmaf(ne, r, pn1); pd1 = fmaf(nr, r, pd1); }
                else        { pn0 = fmaf(ne, r, pn0); pd0 = fmaf(nr, r, pd0); }
            }
            float pn = pn0 + pn1;
            float pd = pd0 + pd1;

            // VALU butterfly over cc (lane bits 4,5): full column sums
            // (seeds sum back exactly: 4 equal power-of-2 fractions)
            pn = red16(pn);  pd = red16(pd);
            pn = red32(pn);  pd = red32(pd);

            // shortened tail: one trans + one mul
            v_my = pn * __builtin_amdgcn_rcpf(pd);

            // publish v; next unfold's seed (cmt*v folded) in the barrier shadow
            if (lane < 16) vbuf[p ^ 1][(w << 4) + lane] = v_my;
            sn = fmaf(cmt4, v_my, nseed);

            lds_barrier();
        }

        // rotate prefetched inputs; motor outputs from lanes 0..2 of wave 0
        xc[0] = p01.x; xc[1] = p01.y; xc[2] = p23.x;
        xc[3] = p23.y; xc[4] = p45.x; xc[5] = p45.y;
        if (t < MOT_) ob[s * MOT_ + t] = fmaf(v_my, OW, OB);
    }
}

extern "C" void kernel_launch(void* const* d_in, const int* in_sizes, int n_in,
                              void* d_out, int out_size, void* d_ws, size_t ws_size,
                              hipStream_t stream) {
    (void)in_sizes; (void)n_in; (void)d_ws; (void)ws_size; (void)out_size;
    const float* x       = (const float*)d_in[0];
    const float* mean_us = (const float*)d_in[1];
    const float* std_us  = (const float*)d_in[2];
    const float* input_w = (const float*)d_in[3];
    const float* input_b = (const float*)d_in[4];
    const float* out_w   = (const float*)d_in[5];
    const float* out_b   = (const float*)d_in[6];
    const float* gleak   = (const float*)d_in[7];
    const float* vleak   = (const float*)d_in[8];
    const float* cm      = (const float*)d_in[9];
    const float* sW      = (const float*)d_in[10];
    const float* sMu     = (const float*)d_in[11];
    const float* sSig    = (const float*)d_in[12];
    const float* sErev   = (const float*)d_in[13];
    const float* W       = (const float*)d_in[14];
    const float* Mu      = (const float*)d_in[15];
    const float* Sig     = (const float*)d_in[16];
    const float* Erev    = (const float*)d_in[17];
    float* out = (float*)d_out;

    ltc_kernel<<<dim3(B_), dim3(256), 0, stream>>>(
        x, mean_us, std_us, input_w, input_b, out_w, out_b,
        gleak, vleak, cm, sW, sMu, sSig, sErev, W, Mu, Sig, Erev, out);
}

// Round 14
// 9204.082 us; speedup vs baseline: 1.0455x; 1.0455x over previous
//
#include <hip/hip_runtime.h>

#define B_ 128
#define S_ 4096
#define IN_ 6
#define N_ 64
#define MOT_ 3
#define UNF 6
#define EPS_ 1e-8f
#define LOG2E 1.4426950408889634f

typedef float v2f __attribute__((ext_vector_type(2)));

// ---- VALU-pipe cross-lane pair-sums over lane bits 4 and 5 ----
__device__ __forceinline__ float red16(float x) {
#if __has_builtin(__builtin_amdgcn_permlane16_swap)
    auto r = __builtin_amdgcn_permlane16_swap(__float_as_int(x), __float_as_int(x),
                                              false, false);
    return __int_as_float((int)r[0]) + __int_as_float((int)r[1]);
#else
    return x + __shfl_xor(x, 16, 64);
#endif
}
__device__ __forceinline__ float red32(float x) {
#if __has_builtin(__builtin_amdgcn_permlane32_swap)
    auto r = __builtin_amdgcn_permlane32_swap(__float_as_int(x), __float_as_int(x),
                                              false, false);
    return __int_as_float((int)r[0]) + __int_as_float((int)r[1]);
#else
    return x + __shfl_xor(x, 32, 64);
#endif
}

// barrier with LDS-only drain (no vmcnt: global loads/stores stay in flight)
__device__ __forceinline__ void lds_barrier() {
    asm volatile("s_waitcnt lgkmcnt(0)" ::: "memory");
    __builtin_amdgcn_s_barrier();
}

// MEASURED-BEST structure (round 9, 9.19 ms = ~897 cy/unfold):
// One workgroup per batch chain. 256 threads = 4 waves = 1 wave/SIMD.
// Wave w owns columns w*16..w*16+15; lane l = (cc=l>>4 j-chunk of 16, ii=l&15
// col). Per unfold: 16 sigmoids/lane with PACKED-f32 arg/add math, split
// accumulators, 2-stage VALU butterfly (permlane16/32_swap), ONE lgkm-only
// barrier. Sensory synapses computed PER-LANE in registers at step start
// (no sensory LDS, no divergent block in the k-loop; all waves uniform).
// Probed-and-rejected alternates: in-stream 2-chain ILP (+73%), wave-TLP
// (+59%), flag dataflow sync (+26%), quad/pair-rational trans cuts (+3-6%),
// own-quad ds_bpermute bypass (+8%) — this point is the latency floor of
// the {4-wave, LDS-exchange, barrier}-structure tradeoff curve.
__launch_bounds__(256, 1)
__global__ void ltc_kernel(
    const float* __restrict__ x,
    const float* __restrict__ mean_us, const float* __restrict__ std_us,
    const float* __restrict__ input_w, const float* __restrict__ input_b,
    const float* __restrict__ output_w, const float* __restrict__ output_b,
    const float* __restrict__ gleak, const float* __restrict__ vleak,
    const float* __restrict__ cm,
    const float* __restrict__ sW, const float* __restrict__ sMu,
    const float* __restrict__ sSig, const float* __restrict__ sErev,
    const float* __restrict__ W, const float* __restrict__ Mu,
    const float* __restrict__ Sig, const float* __restrict__ Erev,
    float* __restrict__ out)
{
    const int b    = blockIdx.x;
    const int t    = threadIdx.x;
    const int lane = t & 63;
    const int w    = t >> 6;      // wave 0..3
    const int cc   = lane >> 4;   // j-chunk 0..3 (16 j's each)
    const int ii   = lane & 15;   // column within wave's block
    const int myCol = (w << 4) + ii;
    const int jb   = cc << 4;

    __shared__ __align__(16) float vbuf[2][N_];

    // --- recurrent synapse params: 16 synapses (j=jb..jb+15) of column myCol,
    // packed in pairs for v_pk_fma: sigmoid((v-mu)*sig) = 1/(1+exp2(v*A + Bc))
    v2f A2[8], B2[8];
    float Wr[16], We[16];
#pragma unroll
    for (int jj = 0; jj < 16; ++jj) {
        int idx = (jb + jj) * N_ + myCol;
        float sg = Sig[idx], m = Mu[idx], ww = W[idx], e = Erev[idx];
        A2[jj >> 1][jj & 1] = -sg * LOG2E;
        B2[jj >> 1][jj & 1] = m * sg * LOG2E;
        Wr[jj] = ww;
        We[jj] = ww * e;
    }

    // --- per-column state consts ---
    const float cmt = cm[myCol] * (float)UNF;
    const float glk = gleak[myCol];
    const float gv  = glk * vleak[myCol];
    const float dbase = cmt + glk + EPS_;

    // --- sensory params: per-lane, ALL 6 inputs for column myCol ---
    float SA[IN_], SB[IN_], SWe[IN_], SWv[IN_], NS[IN_], NB[IN_];
#pragma unroll
    for (int ci = 0; ci < IN_; ++ci) {
        int idx = ci * N_ + myCol;
        float sg = sSig[idx], m = sMu[idx], ww = sW[idx], e = sErev[idx];
        SA[ci]  = -sg * LOG2E;
        SB[ci]  = m * sg * LOG2E;
        SWv[ci] = ww;
        SWe[ci] = ww * e;
        NS[ci]  = input_w[ci] / std_us[ci];
        NB[ci]  = input_b[ci] - mean_us[ci] / std_us[ci] * input_w[ci];
    }

    // --- output consts (lanes 0..2 of wave 0 hold motor columns 0..2) ---
    float OW = 0.f, OB = 0.f;
    if (t < MOT_) {
        OW = output_w[t] * std_us[t];
        OB = output_b[t] * std_us[t] + mean_us[t];
    }

    const float* xb = x + (size_t)b * S_ * IN_;
    float* ob = out + (size_t)b * S_ * MOT_;

    if (t < N_) vbuf[0][t] = 0.f;

    // step-0 inputs (blocking, one-time); force VMEM via VGPR offset
    float xc[IN_];
    {
        int off = 0;
        asm volatile("" : "+v"(off));
        float2 x01 = *(const float2*)(xb + off);
        float2 x23 = *(const float2*)(xb + off + 2);
        float2 x45 = *(const float2*)(xb + off + 4);
        xc[0] = x01.x; xc[1] = x01.y; xc[2] = x23.x;
        xc[3] = x23.y; xc[4] = x45.x; xc[5] = x45.y;
    }
    __syncthreads();

    float v_my = 0.f;

    for (int s = 0; s < S_; ++s) {
        // prefetch next step's inputs (VMEM, stays in flight across lgkm waits)
        const int s1 = (s + 1 < S_) ? (s + 1) : s;
        int off = s1 * IN_;
        asm volatile("" : "+v"(off));
        float2 p01 = *(const float2*)(xb + off);
        float2 p23 = *(const float2*)(xb + off + 2);
        float2 p45 = *(const float2*)(xb + off + 4);

        // per-lane sensory fold for this step (registers only; overlaps k=0's
        // v-read + sigmoid phase, consumed only after k=0's butterfly)
        float wns = 0.f, wds = 0.f;
#pragma unroll
        for (int ci = 0; ci < IN_; ++ci) {
            float u  = fmaf(xc[ci], NS[ci], NB[ci]);
            float e  = __builtin_amdgcn_exp2f(fmaf(u, SA[ci], SB[ci]));
            float sg = __builtin_amdgcn_rcpf(1.0f + e);
            wns = fmaf(SWe[ci], sg, wns);
            wds = fmaf(SWv[ci], sg, wds);
        }
        const float nbs = gv + wns;
        const float dbs = dbase + wds;

#pragma unroll
        for (int k = 0; k < UNF; ++k) {
            const int p = k & 1;
            // broadcast-read the 16 v's of this lane's j-chunk (4x ds_read_b128)
            float4 q0 = *(const float4*)&vbuf[p][jb];
            float4 q1 = *(const float4*)&vbuf[p][jb + 4];
            float4 q2 = *(const float4*)&vbuf[p][jb + 8];
            float4 q3 = *(const float4*)&vbuf[p][jb + 12];
            const v2f vp[8] = {
                {q0.x, q0.y}, {q0.z, q0.w}, {q1.x, q1.y}, {q1.z, q1.w},
                {q2.x, q2.y}, {q2.z, q2.w}, {q3.x, q3.y}, {q3.z, q3.w}};

            float pn0 = 0.f, pd0 = 0.f, pn1 = 0.f, pd1 = 0.f;
#pragma unroll
            for (int pi = 0; pi < 8; ++pi) {
                v2f z  = __builtin_elementwise_fma(vp[pi], A2[pi], B2[pi]); // pk_fma
                v2f e  = {__builtin_amdgcn_exp2f(z.x), __builtin_amdgcn_exp2f(z.y)};
                v2f tt = e + 1.0f;                                          // pk_add
                float s0  = __builtin_amdgcn_rcpf(tt.x);
                float s1x = __builtin_amdgcn_rcpf(tt.y);
                pn0 = fmaf(We[2*pi],   s0,  pn0);
                pd0 = fmaf(Wr[2*pi],   s0,  pd0);
                pn1 = fmaf(We[2*pi+1], s1x, pn1);
                pd1 = fmaf(Wr[2*pi+1], s1x, pd1);
            }
            float pn = pn0 + pn1;
            float pd = pd0 + pd1;

            // VALU butterfly over cc (lane bits 4,5): full column sums
            pn = red16(pn);  pd = red16(pd);
            pn = red32(pn);  pd = red32(pd);

            v_my = fmaf(cmt, v_my, nbs + pn) * __builtin_amdgcn_rcpf(dbs + pd);

            // publish v for next unfold (double-buffered, one writer per column)
            if (lane < 16) vbuf[p ^ 1][(w << 4) + lane] = v_my;

            lds_barrier();
        }

        // rotate prefetched inputs; motor outputs from lanes 0..2 of wave 0
        xc[0] = p01.x; xc[1] = p01.y; xc[2] = p23.x;
        xc[3] = p23.y; xc[4] = p45.x; xc[5] = p45.y;
        if (t < MOT_) ob[s * MOT_ + t] = fmaf(v_my, OW, OB);
    }
}

extern "C" void kernel_launch(void* const* d_in, const int* in_sizes, int n_in,
                              void* d_out, int out_size, void* d_ws, size_t ws_size,
                              hipStream_t stream) {
    (void)in_sizes; (void)n_in; (void)d_ws; (void)ws_size; (void)out_size;
    const float* x       = (const float*)d_in[0];
    const float* mean_us = (const float*)d_in[1];
    const float* std_us  = (const float*)d_in[2];
    const float* input_w = (const float*)d_in[3];
    const float* input_b = (const float*)d_in[4];
    const float* out_w   = (const float*)d_in[5];
    const float* out_b   = (const float*)d_in[6];
    const float* gleak   = (const float*)d_in[7];
    const float* vleak   = (const float*)d_in[8];
    const float* cm      = (const float*)d_in[9];
    const float* sW      = (const float*)d_in[10];
    const float* sMu     = (const float*)d_in[11];
    const float* sSig    = (const float*)d_in[12];
    const float* sErev   = (const float*)d_in[13];
    const float* W       = (const float*)d_in[14];
    const float* Mu      = (const float*)d_in[15];
    const float* Sig     = (const float*)d_in[16];
    const float* Erev    = (const float*)d_in[17];
    float* out = (float*)d_out;

    ltc_kernel<<<dim3(B_), dim3(256), 0, stream>>>(
        x, mean_us, std_us, input_w, input_b, out_w, out_b,
        gleak, vleak, cm, sW, sMu, sSig, sErev, W, Mu, Sig, Erev, out);
}